// Round 1
// 468.824 us; speedup vs baseline: 1.0428x; 1.0428x over previous
//
#include <hip/hip_runtime.h>
#include <hip/hip_bf16.h>
#include <stdint.h>

// Problem constants
#define B_N 1024
#define S_N 65536
#define D_N 512
#define NS 32                 // s-chunks (split-S); grid = 8 batch-blocks x NS = 256 = 1 block/CU
#define SC (S_N / NS)         // 2048 s per block
#define SB 128                // s subtile (P tile = 128 b x 128 s in LDS)
#define NSUB (SC / SB)        // 16

typedef __attribute__((ext_vector_type(8))) short bf16x8;   // 8 bf16 in 4 VGPRs
typedef __attribute__((ext_vector_type(4))) float f32x4;

// ---- workspace layout (bytes) ----
#define OFF_MBF   ((size_t)0)                                  // M bf16 (s,d)   64 MiB
#define OFF_MT    (OFF_MBF + (size_t)S_N * D_N * 2)            // M^T bf16 (d,s) 64 MiB
#define OFF_XBF   (OFF_MT  + (size_t)D_N * S_N * 2)            // X bf16         1 MiB
#define OFF_RX    (OFF_XBF + (size_t)B_N * D_N * 2)            // 8*log2e*rsqrt(|x|^2)  4 KiB
#define OFF_RM    (OFF_RX  + (size_t)B_N * 4)                  // rsqrt(|m|^2)   256 KiB
#define OFF_LSUM  (OFF_RM  + (size_t)S_N * 4)                  // softmax denom  4 KiB
#define OFF_OPART (OFF_LSUM + (size_t)B_N * 4)                 // PV partials    64 MiB
// total ~ 193.3 MiB (was 289.3)

__device__ __forceinline__ unsigned short f2bf(float f) {
  unsigned u = __builtin_bit_cast(unsigned, f);
  u += 0x7fffu + ((u >> 16) & 1u);          // RNE
  return (unsigned short)(u >> 16);
}

__device__ __forceinline__ void stage16(const unsigned short* g, unsigned short* l) {
  // async global->LDS, 16B/lane; LDS dest is wave-uniform base + lane*16
  __builtin_amdgcn_global_load_lds(
      (const __attribute__((address_space(1))) void*)g,
      (__attribute__((address_space(3))) void*)l, 16, 0, 0);
}

// ---------------- prep X: bf16 convert + rx = 8*log2e*rsqrt(||x||^2) ----------------
__global__ void k_prep_x(const float* __restrict__ X, unsigned short* __restrict__ Xbf,
                         float* __restrict__ rx) {
  const int row = blockIdx.x;
  const int t = threadIdx.x;  // 0..127
  float4 v = ((const float4*)(X + (size_t)row * D_N))[t];
  float ss = v.x*v.x + v.y*v.y + v.z*v.z + v.w*v.w;
  ushort4 o; o.x = f2bf(v.x); o.y = f2bf(v.y); o.z = f2bf(v.z); o.w = f2bf(v.w);
  ((ushort4*)(Xbf + (size_t)row * D_N))[t] = o;
  #pragma unroll
  for (int m = 1; m < 64; m <<= 1) ss += __shfl_xor(ss, m);
  __shared__ float partial[2];
  if ((t & 63) == 0) partial[t >> 6] = ss;
  __syncthreads();
  // 8 * log2(e) = 11.5415603...; exponent computed as exp2(dot * rx * rm)
  if (t == 0) rx[row] = 11.541560327111707f * rsqrtf(fmaxf(partial[0] + partial[1], 1e-24f));
}

// ------- prep M: bf16 convert, LDS-transpose to Mt, rm = rsqrt(||m||^2) -------
__global__ void k_prep_m(const float* __restrict__ M, unsigned short* __restrict__ Mbf,
                         unsigned short* __restrict__ Mt, float* __restrict__ rm) {
  __shared__ float ts[64 * 65];             // 64x64 tile, +1 pad -> conflict-free transpose
  const int t = threadIdx.x;                // 256
  const int s0 = blockIdx.x * 64;
  const int r = t >> 2, cq = t & 3;         // load role: row r, 16-col chunk cq
  const int c = t >> 2, sq = t & 3;         // store role: Mt row c, 16-s chunk sq
  float ss = 0.f;
  for (int ct = 0; ct < 8; ++ct) {
    float f[16];
    const float4* src = (const float4*)(M + (size_t)(s0 + r) * D_N + ct * 64 + cq * 16);
    #pragma unroll
    for (int k = 0; k < 4; ++k) {
      float4 v = src[k];
      f[4*k+0] = v.x; f[4*k+1] = v.y; f[4*k+2] = v.z; f[4*k+3] = v.w;
    }
    union { unsigned short u[16]; uint4 v4[2]; } pk;
    #pragma unroll
    for (int j = 0; j < 16; ++j) {
      ss += f[j] * f[j];
      pk.u[j] = f2bf(f[j]);
      ts[r * 65 + cq * 16 + j] = f[j];
    }
    uint4* dst = (uint4*)(Mbf + (size_t)(s0 + r) * D_N + ct * 64 + cq * 16);
    dst[0] = pk.v4[0]; dst[1] = pk.v4[1];
    __syncthreads();
    union { unsigned short u[16]; uint4 v4[2]; } pt;
    #pragma unroll
    for (int j = 0; j < 16; ++j) pt.u[j] = f2bf(ts[(sq * 16 + j) * 65 + c]);
    uint4* dt = (uint4*)(Mt + (size_t)(ct * 64 + c) * S_N + s0 + sq * 16);
    dt[0] = pt.v4[0]; dt[1] = pt.v4[1];
    __syncthreads();
  }
  ss += __shfl_xor(ss, 1);
  ss += __shfl_xor(ss, 2);
  if (cq == 0) rm[s0 + r] = rsqrtf(fmaxf(ss, 1e-24f));
}

// ================= fused QK -> exp -> PV =================
// Per block: batch tile 128, s-chunk SC=2048, looped in SB=128 subtiles.
// QK uses SWAPPED operands (A-side = M rows, B-side = X rows) so the MFMA C
// layout C[s,b] gives each lane 4 s-consecutive P values per fragment ->
// packed 8B writes into a swizzled P-LDS [b][s] tile. PV then consumes P-LDS
// as A-operand fragments (same verified read pattern as the old k_pv) against
// staged Mt chunks, accumulating O(128x512) in registers for the whole chunk.
// LDS: 32 KiB staging (QK A/B tiles, reused for PV Mt chunks) + 32 KiB P.
// All LDS tiles use the verified XOR-chunk swizzle: phys16Bchunk = c ^ (row&7).
__global__ __launch_bounds__(512, 2) void k_fused(
    const unsigned short* __restrict__ Xbf, const unsigned short* __restrict__ Mbf,
    const unsigned short* __restrict__ Mt, const float* __restrict__ rx,
    const float* __restrict__ rminv, float* __restrict__ lsum,
    float* __restrict__ Opart) {
  __shared__ unsigned short smem[16384];   // 32 KiB: [As 128x64 | Bs 128x64] or Mt chunk 128x128
  __shared__ unsigned short Ps[16384];     // 32 KiB: P tile, rows b (128), 128 s bf16, swizzled

  const int t = threadIdx.x;               // 0..511
  const int w = t >> 6, lane = t & 63, quad = lane >> 4, l15 = lane & 15;
  const int qr = w >> 1, qc = w & 1;       // wave grid 4x2 (s x b for QK; b x d for PV)
  const int x7 = l15 & 7;

  // XCD swizzle: the 8 batch-blocks sharing an s-chunk land on one XCD
  // (chunk working set M+Mt = 4 MiB = one XCD L2).
  const int bid = blockIdx.x;
  const int xcd = bid & 7, slot = bid >> 3;        // round-robin dispatch assumption (perf-only)
  const int bblk = slot & 7;
  const int chunk = xcd * 4 + (slot >> 3);         // 0..31
  const int b0 = bblk * 128;
  const int s0 = chunk * SC;

  unsigned short* As = smem;               // M tile  128 x 64 (QK A-side)
  unsigned short* Bs = smem + 8192;        // X tile  128 x 64 (QK B-side)

  f32x4 accO[4][2][4];                     // O accumulator: (d-chunk, i, j) = 128 VGPR
  #pragma unroll
  for (int dc = 0; dc < 4; ++dc)
    #pragma unroll
    for (int i = 0; i < 2; ++i)
      #pragma unroll
      for (int j = 0; j < 4; ++j) accO[dc][i][j] = (f32x4){0.f, 0.f, 0.f, 0.f};

  float ls[4] = {0.f, 0.f, 0.f, 0.f};      // row-sum partials, b = b0 + qc*64 + j*16 + l15
  float rxj[4];
  #pragma unroll
  for (int j = 0; j < 4; ++j) rxj[j] = rx[b0 + qc * 64 + j * 16 + l15];

  // stager roles
  const int srow8 = t >> 3;                                 // QK: 64 rows/issue, 8x16B chunks
  const int sch8  = ((t & 7) ^ (srow8 & 7)) * 8;            // source-side inverse swizzle
  const unsigned short* gX = Xbf + (size_t)(b0 + srow8) * D_N + sch8;
  const int mrow = t >> 4;                                  // PV: 32 rows/issue, 16x16B chunks
  const int mch  = ((t & 15) ^ (mrow & 7)) * 8;

  for (int sub = 0; sub < NSUB; ++sub) {
    const int sS = s0 + sub * SB;

    // ---------------- QK: P^T(s,b) = M(128s x 512) * X(128b x 512)^T ----------------
    f32x4 accP[2][4];
    #pragma unroll
    for (int i = 0; i < 2; ++i)
      #pragma unroll
      for (int j = 0; j < 4; ++j) accP[i][j] = (f32x4){0.f, 0.f, 0.f, 0.f};

    const unsigned short* gM = Mbf + (size_t)(sS + srow8) * D_N + sch8;
    for (int k0 = 0; k0 < D_N; k0 += 64) {
      stage16(gM + k0,                      As + w * 512);
      stage16(gM + (size_t)64 * D_N + k0,   As + 4096 + w * 512);
      stage16(gX + k0,                      Bs + w * 512);
      stage16(gX + (size_t)64 * D_N + k0,   Bs + 4096 + w * 512);
      __syncthreads();
      #pragma unroll
      for (int kk = 0; kk < 64; kk += 32) {
        const int cq = (kk >> 3) + quad;
        bf16x8 a[2], b[4];
        #pragma unroll
        for (int i = 0; i < 2; ++i)
          a[i] = *(const bf16x8*)&As[(qr * 32 + i * 16 + l15) * 64 + ((cq ^ x7) << 3)];
        #pragma unroll
        for (int j = 0; j < 4; ++j)
          b[j] = *(const bf16x8*)&Bs[(qc * 64 + j * 16 + l15) * 64 + ((cq ^ x7) << 3)];
        #pragma unroll
        for (int i = 0; i < 2; ++i)
          #pragma unroll
          for (int j = 0; j < 4; ++j)
            accP[i][j] = __builtin_amdgcn_mfma_f32_16x16x32_bf16(a[i], b[j], accP[i][j], 0, 0, 0);
      }
      __syncthreads();
    }

    // ------------- epilogue: p = exp2(dot * rx_b * rm_s), rowsum, P -> LDS -------------
    // C layout: s = qr*32 + i*16 + quad*4 + r (4 consecutive per frag!), b = qc*64 + j*16 + l15
    const float4 rm0 = *(const float4*)&rminv[sS + qr * 32 + quad * 4];
    const float4 rm1 = *(const float4*)&rminv[sS + qr * 32 + 16 + quad * 4];
    #pragma unroll
    for (int i = 0; i < 2; ++i) {
      const float4 rm = i ? rm1 : rm0;
      const int sl  = qr * 32 + i * 16 + quad * 4;   // local s base (mult of 4)
      const int c16 = sl >> 3;                        // 16B chunk (0..15)
      const int o8  = (sl >> 2) & 1;                  // 8B half within chunk
      #pragma unroll
      for (int j = 0; j < 4; ++j) {
        const float p0 = exp2f(accP[i][j][0] * rxj[j] * rm.x);
        const float p1 = exp2f(accP[i][j][1] * rxj[j] * rm.y);
        const float p2 = exp2f(accP[i][j][2] * rxj[j] * rm.z);
        const float p3 = exp2f(accP[i][j][3] * rxj[j] * rm.w);
        ls[j] += (p0 + p1) + (p2 + p3);
        const int brow = qc * 64 + j * 16 + l15;
        uint2 pk;
        pk.x = (unsigned)f2bf(p0) | ((unsigned)f2bf(p1) << 16);
        pk.y = (unsigned)f2bf(p2) | ((unsigned)f2bf(p3) << 16);
        *(uint2*)&Ps[brow * 128 + (((c16 ^ (brow & 7)) << 3) | (o8 << 2))] = pk;
      }
    }
    __syncthreads();   // P ready; staging LDS free

    // ---------------- PV: O(128b x 512d) += P(128b x 128s) * Mt(512d x 128s)^T ----------------
    #pragma unroll
    for (int dc = 0; dc < 4; ++dc) {
      const unsigned short* gT = Mt + (size_t)(dc * 128 + mrow) * S_N + sS + mch;
      stage16(gT,                      smem + w * 512);
      stage16(gT + (size_t)32 * S_N,   smem + 4096 + w * 512);
      stage16(gT + (size_t)64 * S_N,   smem + 8192 + w * 512);
      stage16(gT + (size_t)96 * S_N,   smem + 12288 + w * 512);
      __syncthreads();
      #pragma unroll
      for (int kk = 0; kk < 128; kk += 32) {
        const int cq = (kk >> 3) + quad;
        bf16x8 pa[2], mb[4];
        #pragma unroll
        for (int i = 0; i < 2; ++i)
          pa[i] = *(const bf16x8*)&Ps[(qr * 32 + i * 16 + l15) * 128 + ((cq ^ x7) << 3)];
        #pragma unroll
        for (int j = 0; j < 4; ++j)
          mb[j] = *(const bf16x8*)&smem[(qc * 64 + j * 16 + l15) * 128 + ((cq ^ x7) << 3)];
        #pragma unroll
        for (int i = 0; i < 2; ++i)
          #pragma unroll
          for (int j = 0; j < 4; ++j)
            accO[dc][i][j] = __builtin_amdgcn_mfma_f32_16x16x32_bf16(pa[i], mb[j], accO[dc][i][j], 0, 0, 0);
      }
      __syncthreads();
    }
  }

  // ---------------- write O partials (coalesced over d via l15) ----------------
  float* Od = Opart + (size_t)chunk * ((size_t)B_N * D_N);
  #pragma unroll
  for (int dc = 0; dc < 4; ++dc)
    #pragma unroll
    for (int i = 0; i < 2; ++i)
      #pragma unroll
      for (int r = 0; r < 4; ++r) {
        const int bb = b0 + qr * 32 + i * 16 + quad * 4 + r;
        #pragma unroll
        for (int j = 0; j < 4; ++j) {
          const int d = dc * 128 + qc * 64 + j * 16 + l15;
          Od[(size_t)bb * D_N + d] = accO[dc][i][j][r];
        }
      }

  // ---------------- lsum: quad-reduce, cross-wave via LDS, one atomic per b ----------------
  __syncthreads();
  float* red = (float*)smem;                 // 8 waves x 64 b-slots
  #pragma unroll
  for (int j = 0; j < 4; ++j) {
    float v = ls[j];
    v += __shfl_xor(v, 16);
    v += __shfl_xor(v, 32);
    if (lane < 16) red[w * 64 + j * 16 + lane] = v;
  }
  __syncthreads();
  if (t < 128) {
    const int qc2 = t >> 6, idx = t & 63;
    float s = red[(0 + qc2) * 64 + idx] + red[(2 + qc2) * 64 + idx] +
              red[(4 + qc2) * 64 + idx] + red[(6 + qc2) * 64 + idx];
    unsafeAtomicAdd(&lsum[b0 + t], s);
  }
}

// ---------------- combine: out = (sum_ks Opart) / lsum ----------------
__global__ void k_combine(const float* __restrict__ Opart, const float* __restrict__ lsum,
                          float* __restrict__ out) {
  const int idx = blockIdx.x * 256 + threadIdx.x;  // float4 index, 131072 total
  const int b = idx >> 7;                          // (idx*4)/512
  float4 s = {0.f, 0.f, 0.f, 0.f};
  #pragma unroll
  for (int ks = 0; ks < NS; ++ks) {
    float4 v = ((const float4*)Opart)[(size_t)ks * (B_N * D_N / 4) + idx];
    s.x += v.x; s.y += v.y; s.z += v.z; s.w += v.w;
  }
  const float inv = 1.0f / lsum[b];
  s.x *= inv; s.y *= inv; s.z *= inv; s.w *= inv;
  ((float4*)out)[idx] = s;
}

extern "C" void kernel_launch(void* const* d_in, const int* in_sizes, int n_in,
                              void* d_out, int out_size, void* d_ws, size_t ws_size,
                              hipStream_t stream) {
  const float* X = (const float*)d_in[0];
  const float* M = (const float*)d_in[1];
  char* ws = (char*)d_ws;
  unsigned short* Mbf = (unsigned short*)(ws + OFF_MBF);
  unsigned short* Mt  = (unsigned short*)(ws + OFF_MT);
  unsigned short* Xbf = (unsigned short*)(ws + OFF_XBF);
  float* rxv  = (float*)(ws + OFF_RX);
  float* rmv  = (float*)(ws + OFF_RM);
  float* lsum = (float*)(ws + OFF_LSUM);
  float* Opart = (float*)(ws + OFF_OPART);

  hipMemsetAsync(lsum, 0, B_N * sizeof(float), stream);
  k_prep_x<<<dim3(B_N), 128, 0, stream>>>(X, Xbf, rxv);
  k_prep_m<<<dim3(S_N / 64), 256, 0, stream>>>(M, Mbf, Mt, rmv);
  k_fused<<<dim3(8 * NS), 512, 0, stream>>>(Xbf, Mbf, Mt, rxv, rmv, lsum, Opart);
  k_combine<<<dim3(B_N * D_N / 4 / 256), 256, 0, stream>>>(Opart, lsum, (float*)d_out);
}

// Round 2
// 429.615 us; speedup vs baseline: 1.1379x; 1.0913x over previous
//
#include <hip/hip_runtime.h>
#include <hip/hip_bf16.h>
#include <stdint.h>

// Problem constants
#define B_N 1024
#define S_N 65536
#define D_N 512
#define NS 32                 // s-chunks (split-S); grid = 8 batch-blocks x NS = 256 = 1 block/CU
#define SC (S_N / NS)         // 2048 s per block
#define SB 128                // s subtile (P tile = 128 b x 128 s in LDS)
#define NSUB (SC / SB)        // 16

typedef __attribute__((ext_vector_type(8))) short bf16x8;   // 8 bf16 in 4 VGPRs
typedef __attribute__((ext_vector_type(4))) float f32x4;

// ---- workspace layout (bytes) ----
#define OFF_MBF   ((size_t)0)                                  // M bf16 (s,d)   64 MiB
#define OFF_MT    (OFF_MBF + (size_t)S_N * D_N * 2)            // M^T bf16 (d,s) 64 MiB
#define OFF_XBF   (OFF_MT  + (size_t)D_N * S_N * 2)            // X bf16         1 MiB
#define OFF_RX    (OFF_XBF + (size_t)B_N * D_N * 2)            // 8*log2e*rsqrt(|x|^2)  4 KiB
#define OFF_RM    (OFF_RX  + (size_t)B_N * 4)                  // rsqrt(|m|^2)   256 KiB
#define OFF_LSUM  (OFF_RM  + (size_t)S_N * 4)                  // softmax denom  4 KiB
#define OFF_OPART (OFF_LSUM + (size_t)B_N * 4)                 // PV partials    64 MiB

__device__ __forceinline__ unsigned short f2bf(float f) {
  unsigned u = __builtin_bit_cast(unsigned, f);
  u += 0x7fffu + ((u >> 16) & 1u);          // RNE
  return (unsigned short)(u >> 16);
}

__device__ __forceinline__ void stage16(const unsigned short* g, unsigned short* l) {
  // async global->LDS, 16B/lane; LDS dest is wave-uniform base + lane*16
  __builtin_amdgcn_global_load_lds(
      (const __attribute__((address_space(1))) void*)g,
      (__attribute__((address_space(3))) void*)l, 16, 0, 0);
}

// ---------------- prep X: bf16 convert + rx = 8*log2e*rsqrt(||x||^2) ----------------
__global__ void k_prep_x(const float* __restrict__ X, unsigned short* __restrict__ Xbf,
                         float* __restrict__ rx) {
  const int row = blockIdx.x;
  const int t = threadIdx.x;  // 0..127
  float4 v = ((const float4*)(X + (size_t)row * D_N))[t];
  float ss = v.x*v.x + v.y*v.y + v.z*v.z + v.w*v.w;
  ushort4 o; o.x = f2bf(v.x); o.y = f2bf(v.y); o.z = f2bf(v.z); o.w = f2bf(v.w);
  ((ushort4*)(Xbf + (size_t)row * D_N))[t] = o;
  #pragma unroll
  for (int m = 1; m < 64; m <<= 1) ss += __shfl_xor(ss, m);
  __shared__ float partial[2];
  if ((t & 63) == 0) partial[t >> 6] = ss;
  __syncthreads();
  if (t == 0) rx[row] = 11.541560327111707f * rsqrtf(fmaxf(partial[0] + partial[1], 1e-24f));
}

// ------- prep M: bf16 convert, LDS-transpose to Mt, rm = rsqrt(||m||^2) -------
__global__ void k_prep_m(const float* __restrict__ M, unsigned short* __restrict__ Mbf,
                         unsigned short* __restrict__ Mt, float* __restrict__ rm) {
  __shared__ float ts[64 * 65];             // 64x64 tile, +1 pad -> conflict-free transpose
  const int t = threadIdx.x;                // 256
  const int s0 = blockIdx.x * 64;
  const int r = t >> 2, cq = t & 3;
  const int c = t >> 2, sq = t & 3;
  float ss = 0.f;
  for (int ct = 0; ct < 8; ++ct) {
    float f[16];
    const float4* src = (const float4*)(M + (size_t)(s0 + r) * D_N + ct * 64 + cq * 16);
    #pragma unroll
    for (int k = 0; k < 4; ++k) {
      float4 v = src[k];
      f[4*k+0] = v.x; f[4*k+1] = v.y; f[4*k+2] = v.z; f[4*k+3] = v.w;
    }
    union { unsigned short u[16]; uint4 v4[2]; } pk;
    #pragma unroll
    for (int j = 0; j < 16; ++j) {
      ss += f[j] * f[j];
      pk.u[j] = f2bf(f[j]);
      ts[r * 65 + cq * 16 + j] = f[j];
    }
    uint4* dst = (uint4*)(Mbf + (size_t)(s0 + r) * D_N + ct * 64 + cq * 16);
    dst[0] = pk.v4[0]; dst[1] = pk.v4[1];
    __syncthreads();
    union { unsigned short u[16]; uint4 v4[2]; } pt;
    #pragma unroll
    for (int j = 0; j < 16; ++j) pt.u[j] = f2bf(ts[(sq * 16 + j) * 65 + c]);
    uint4* dt = (uint4*)(Mt + (size_t)(ct * 64 + c) * S_N + s0 + sq * 16);
    dt[0] = pt.v4[0]; dt[1] = pt.v4[1];
    __syncthreads();
  }
  ss += __shfl_xor(ss, 1);
  ss += __shfl_xor(ss, 2);
  if (cq == 0) rm[s0 + r] = rsqrtf(fmaxf(ss, 1e-24f));
}

// ================= fused QK -> exp -> PV, software-pipelined staging =================
// 12 stage-phases per sub (8 QK k0-steps + 4 PV dc-steps) run as one continuous
// pipeline: phase t's compute overlaps phase t+1's global_load_lds into the
// other of two 32 KiB staging buffers. Raw s_barrier + counted s_waitcnt
// vmcnt(4) (4 loads/thread/phase) -- loads stay in flight across barriers;
// vmcnt(0) only at the very last phase. Ps visibility via explicit lgkmcnt(0).
__global__ __launch_bounds__(512, 2) void k_fused(
    const unsigned short* __restrict__ Xbf, const unsigned short* __restrict__ Mbf,
    const unsigned short* __restrict__ Mt, const float* __restrict__ rx,
    const float* __restrict__ rminv, float* __restrict__ lsum,
    float* __restrict__ Opart) {
  __shared__ unsigned short sbuf[2][16384]; // 2 x 32 KiB staging (QK: A|B, PV: Mt chunk)
  __shared__ unsigned short Ps[16384];      // 32 KiB P tile, swizzled

  const int t = threadIdx.x;               // 0..511
  const int w = t >> 6, lane = t & 63, quad = lane >> 4, l15 = lane & 15;
  const int qr = w >> 1, qc = w & 1;       // wave grid 4x2 (s x b for QK; b x d for PV)
  const int x7 = l15 & 7;

  // XCD swizzle: 8 batch-blocks sharing an s-chunk land on one XCD (M+Mt chunk = 4 MiB L2)
  const int bid = blockIdx.x;
  const int xcd = bid & 7, slot = bid >> 3;
  const int bblk = slot & 7;
  const int chunk = xcd * 4 + (slot >> 3);
  const int b0 = bblk * 128;
  const int s0 = chunk * SC;

  f32x4 accO[4][2][4];                     // O accumulator (d-chunk, i, j)
  #pragma unroll
  for (int dc = 0; dc < 4; ++dc)
    #pragma unroll
    for (int i = 0; i < 2; ++i)
      #pragma unroll
      for (int j = 0; j < 4; ++j) accO[dc][i][j] = (f32x4){0.f, 0.f, 0.f, 0.f};

  float ls[4] = {0.f, 0.f, 0.f, 0.f};
  float rxj[4];
  #pragma unroll
  for (int j = 0; j < 4; ++j) rxj[j] = rx[b0 + qc * 64 + j * 16 + l15];

  // stager roles
  const int srow8 = t >> 3;                                 // QK: 64 rows/issue, 8x16B chunks
  const int sch8  = ((t & 7) ^ (srow8 & 7)) * 8;            // source-side inverse swizzle
  const unsigned short* gX0 = Xbf + (size_t)(b0 + srow8) * D_N + sch8;   // + k0
  const unsigned short* gM0 = Mbf + (size_t)srow8 * D_N + sch8;          // + sS*D_N + k0
  const int mrow = t >> 4;                                  // PV: 32 rows/issue, 16x16B chunks
  const int mch  = ((t & 15) ^ (mrow & 7)) * 8;
  const unsigned short* gT0 = Mt + (size_t)mrow * S_N + mch;             // + dc*128*S_N + sS

  #define ISSUE_QK(sS_, k0_, bi_) do {                                       \
    unsigned short* bA_ = &sbuf[(bi_)][0];                                   \
    unsigned short* bB_ = &sbuf[(bi_)][8192];                                \
    const unsigned short* gM_ = gM0 + (size_t)(sS_) * D_N + (k0_);           \
    stage16(gM_,                   bA_ + w * 512);                           \
    stage16(gM_ + (size_t)64*D_N,  bA_ + 4096 + w * 512);                    \
    const unsigned short* gX_ = gX0 + (k0_);                                 \
    stage16(gX_,                   bB_ + w * 512);                           \
    stage16(gX_ + (size_t)64*D_N,  bB_ + 4096 + w * 512);                    \
  } while (0)

  #define ISSUE_PV(sS_, dc_, bi_) do {                                       \
    unsigned short* bT_ = &sbuf[(bi_)][0];                                   \
    const unsigned short* gT_ = gT0 + (size_t)((dc_) * 128) * S_N + (sS_);   \
    stage16(gT_,                   bT_ + w * 512);                           \
    stage16(gT_ + (size_t)32*S_N,  bT_ + 4096 + w * 512);                    \
    stage16(gT_ + (size_t)64*S_N,  bT_ + 8192 + w * 512);                    \
    stage16(gT_ + (size_t)96*S_N,  bT_ + 12288 + w * 512);                   \
  } while (0)

  // prologue: phase 0 (sub 0, k0=0) into buffer 0
  ISSUE_QK(s0, 0, 0);

  for (int sub = 0; sub < NSUB; ++sub) {
    const int sS = s0 + sub * SB;

    // ---------------- QK phases 0..7 ----------------
    f32x4 accP[2][4];
    #pragma unroll
    for (int i = 0; i < 2; ++i)
      #pragma unroll
      for (int j = 0; j < 4; ++j) accP[i][j] = (f32x4){0.f, 0.f, 0.f, 0.f};

    #pragma unroll
    for (int st = 0; st < 8; ++st) {
      const int bi = st & 1;
      if (st < 7) { ISSUE_QK(sS, (st + 1) * 64, bi ^ 1); }
      else        { ISSUE_PV(sS, 0, bi ^ 1); }
      asm volatile("s_waitcnt vmcnt(4)" ::: "memory");
      __builtin_amdgcn_s_barrier();
      const unsigned short* As = &sbuf[bi][0];
      const unsigned short* Bs = &sbuf[bi][8192];
      __builtin_amdgcn_s_setprio(1);
      #pragma unroll
      for (int kk = 0; kk < 64; kk += 32) {
        const int cq = (kk >> 3) + quad;
        bf16x8 a[2], b[4];
        #pragma unroll
        for (int i = 0; i < 2; ++i)
          a[i] = *(const bf16x8*)&As[(qr * 32 + i * 16 + l15) * 64 + ((cq ^ x7) << 3)];
        #pragma unroll
        for (int j = 0; j < 4; ++j)
          b[j] = *(const bf16x8*)&Bs[(qc * 64 + j * 16 + l15) * 64 + ((cq ^ x7) << 3)];
        #pragma unroll
        for (int i = 0; i < 2; ++i)
          #pragma unroll
          for (int j = 0; j < 4; ++j)
            accP[i][j] = __builtin_amdgcn_mfma_f32_16x16x32_bf16(a[i], b[j], accP[i][j], 0, 0, 0);
      }
      __builtin_amdgcn_s_setprio(0);
      __builtin_amdgcn_s_barrier();
    }

    // ------------- epilogue: p = exp2(dot * rx_b * rm_s), rowsum, P -> LDS -------------
    {
      const float4 rm0 = *(const float4*)&rminv[sS + qr * 32 + quad * 4];
      const float4 rm1 = *(const float4*)&rminv[sS + qr * 32 + 16 + quad * 4];
      #pragma unroll
      for (int i = 0; i < 2; ++i) {
        const float4 rm = i ? rm1 : rm0;
        const int sl  = qr * 32 + i * 16 + quad * 4;
        const int c16 = sl >> 3;
        const int o8  = (sl >> 2) & 1;
        #pragma unroll
        for (int j = 0; j < 4; ++j) {
          const float p0 = exp2f(accP[i][j][0] * rxj[j] * rm.x);
          const float p1 = exp2f(accP[i][j][1] * rxj[j] * rm.y);
          const float p2 = exp2f(accP[i][j][2] * rxj[j] * rm.z);
          const float p3 = exp2f(accP[i][j][3] * rxj[j] * rm.w);
          ls[j] += (p0 + p1) + (p2 + p3);
          const int brow = qc * 64 + j * 16 + l15;
          uint2 pk;
          pk.x = (unsigned)f2bf(p0) | ((unsigned)f2bf(p1) << 16);
          pk.y = (unsigned)f2bf(p2) | ((unsigned)f2bf(p3) << 16);
          *(uint2*)&Ps[brow * 128 + (((c16 ^ (brow & 7)) << 3) | (o8 << 2))] = pk;
        }
      }
      asm volatile("s_waitcnt lgkmcnt(0)" ::: "memory");  // Ps writes visible before barrier
    }

    // ---------------- PV phases 8..11 ----------------
    #pragma unroll
    for (int dc = 0; dc < 4; ++dc) {
      const int bi = dc & 1;    // phase (8+dc)&1
      if (dc < 3)                  { ISSUE_PV(sS, dc + 1, bi ^ 1); }
      else if (sub < NSUB - 1)     { ISSUE_QK(sS + SB, 0, bi ^ 1); }
      if (dc == 3 && sub == NSUB - 1) asm volatile("s_waitcnt vmcnt(0)" ::: "memory");
      else                            asm volatile("s_waitcnt vmcnt(4)" ::: "memory");
      __builtin_amdgcn_s_barrier();
      const unsigned short* Tsb = &sbuf[bi][0];
      __builtin_amdgcn_s_setprio(1);
      #pragma unroll
      for (int kk = 0; kk < 128; kk += 32) {
        const int cq = (kk >> 3) + quad;
        bf16x8 pa[2], mb[4];
        #pragma unroll
        for (int i = 0; i < 2; ++i)
          pa[i] = *(const bf16x8*)&Ps[(qr * 32 + i * 16 + l15) * 128 + ((cq ^ x7) << 3)];
        #pragma unroll
        for (int j = 0; j < 4; ++j)
          mb[j] = *(const bf16x8*)&Tsb[(qc * 64 + j * 16 + l15) * 128 + ((cq ^ x7) << 3)];
        #pragma unroll
        for (int i = 0; i < 2; ++i)
          #pragma unroll
          for (int j = 0; j < 4; ++j)
            accO[dc][i][j] = __builtin_amdgcn_mfma_f32_16x16x32_bf16(pa[i], mb[j], accO[dc][i][j], 0, 0, 0);
      }
      __builtin_amdgcn_s_setprio(0);
      __builtin_amdgcn_s_barrier();
    }
  }

  // ---------------- write O partials (coalesced over d via l15) ----------------
  float* Od = Opart + (size_t)chunk * ((size_t)B_N * D_N);
  #pragma unroll
  for (int dc = 0; dc < 4; ++dc)
    #pragma unroll
    for (int i = 0; i < 2; ++i)
      #pragma unroll
      for (int r = 0; r < 4; ++r) {
        const int bb = b0 + qr * 32 + i * 16 + quad * 4 + r;
        #pragma unroll
        for (int j = 0; j < 4; ++j) {
          const int d = dc * 128 + qc * 64 + j * 16 + l15;
          Od[(size_t)bb * D_N + d] = accO[dc][i][j][r];
        }
      }

  // ---------------- lsum: quad-reduce, cross-wave via LDS, one atomic per b ----------------
  __syncthreads();
  float* red = (float*)&sbuf[0][0];          // 8 waves x 64 b-slots
  #pragma unroll
  for (int j = 0; j < 4; ++j) {
    float v = ls[j];
    v += __shfl_xor(v, 16);
    v += __shfl_xor(v, 32);
    if (lane < 16) red[w * 64 + j * 16 + lane] = v;
  }
  __syncthreads();
  if (t < 128) {
    const int qc2 = t >> 6, idx = t & 63;
    float s = red[(0 + qc2) * 64 + idx] + red[(2 + qc2) * 64 + idx] +
              red[(4 + qc2) * 64 + idx] + red[(6 + qc2) * 64 + idx];
    unsafeAtomicAdd(&lsum[b0 + t], s);
  }
  #undef ISSUE_QK
  #undef ISSUE_PV
}

// ---------------- combine: out = (sum_ks Opart) / lsum ----------------
__global__ void k_combine(const float* __restrict__ Opart, const float* __restrict__ lsum,
                          float* __restrict__ out) {
  const int idx = blockIdx.x * 256 + threadIdx.x;  // float4 index, 131072 total
  const int b = idx >> 7;
  float4 s = {0.f, 0.f, 0.f, 0.f};
  #pragma unroll
  for (int ks = 0; ks < NS; ++ks) {
    float4 v = ((const float4*)Opart)[(size_t)ks * (B_N * D_N / 4) + idx];
    s.x += v.x; s.y += v.y; s.z += v.z; s.w += v.w;
  }
  const float inv = 1.0f / lsum[b];
  s.x *= inv; s.y *= inv; s.z *= inv; s.w *= inv;
  ((float4*)out)[idx] = s;
}

extern "C" void kernel_launch(void* const* d_in, const int* in_sizes, int n_in,
                              void* d_out, int out_size, void* d_ws, size_t ws_size,
                              hipStream_t stream) {
  const float* X = (const float*)d_in[0];
  const float* M = (const float*)d_in[1];
  char* ws = (char*)d_ws;
  unsigned short* Mbf = (unsigned short*)(ws + OFF_MBF);
  unsigned short* Mt  = (unsigned short*)(ws + OFF_MT);
  unsigned short* Xbf = (unsigned short*)(ws + OFF_XBF);
  float* rxv  = (float*)(ws + OFF_RX);
  float* rmv  = (float*)(ws + OFF_RM);
  float* lsum = (float*)(ws + OFF_LSUM);
  float* Opart = (float*)(ws + OFF_OPART);

  hipMemsetAsync(lsum, 0, B_N * sizeof(float), stream);
  k_prep_x<<<dim3(B_N), 128, 0, stream>>>(X, Xbf, rxv);
  k_prep_m<<<dim3(S_N / 64), 256, 0, stream>>>(M, Mbf, Mt, rmv);
  k_fused<<<dim3(8 * NS), 512, 0, stream>>>(Xbf, Mbf, Mt, rxv, rmv, lsum, Opart);
  k_combine<<<dim3(B_N * D_N / 4 / 256), 256, 0, stream>>>(Opart, lsum, (float*)d_out);
}